// Round 8
// baseline (119.256 us; speedup 1.0000x reference)
//
#include <hip/hip_runtime.h>

// VQ-VAE VectorQuantizer forward, MI355X (gfx950)
// Round 8: FULLY FUSED scan — codebook slices iterated in-block (single-buffer
// LDS restaged from L2-hot ws), argmax across all 1024 codes in registers,
// epilogue (idx, loss, quantized gather) fused. No merge kernel, no partial
// round-trip, x read exactly once.
// out (f32 flat): [0..4194304) quantized, [4194304] loss,
//                 [4194305..+65536) indices (as float), [4259841..+65536) w.T

#define N_VEC 65536
#define D 64
#define K 1024
#define BETA 0.25f

#define OFF_Q    0
#define OFF_LOSS 4194304
#define OFF_IDX  4194305
#define OFF_WT   4259841

#define WS_WHI  0         // 128 KB frag-ordered fp16 hi plane
#define WS_WLO  131072    // 128 KB lo plane
#define WS_HNEG 262144    // 4 KB  -0.5*||w||^2 (f32)

typedef _Float16 v8h __attribute__((ext_vector_type(8)));
typedef float v16f __attribute__((ext_vector_type(16)));
typedef __attribute__((address_space(3))) void lds_void_t;
typedef __attribute__((address_space(1))) const void gbl_void_t;

// ---------------- prep (proven): w^T, frag fp16 hi/lo, hneg, loss=0
__global__ __launch_bounds__(256) void vq_prep(const float* __restrict__ w,
                                               char* __restrict__ ws,
                                               float* __restrict__ out) {
  __shared__ float s[2048];
  const int t = blockIdx.x, tid = threadIdx.x;

  const float4* src = (const float4*)(w + (size_t)t * 2048);
  float4 a = src[tid];
  float4 b = src[tid + 256];
  ((float4*)s)[tid] = a;
  ((float4*)s)[tid + 256] = b;

  float p0 = a.x * a.x + a.y * a.y + a.z * a.z + a.w * a.w;
  float p1 = b.x * b.x + b.y * b.y + b.z * b.z + b.w * b.w;
#pragma unroll
  for (int m = 1; m <= 8; m <<= 1) {
    p0 += __shfl_xor(p0, m, 64);
    p1 += __shfl_xor(p1, m, 64);
  }
  float* hn = (float*)(ws + WS_HNEG);
  if ((tid & 15) == 0) {
    hn[t * 32 + (tid >> 4)] = -0.5f * p0;
    hn[t * 32 + 16 + (tid >> 4)] = -0.5f * p1;
  }
  if (t == 0 && tid == 0) out[OFF_LOSS] = 0.f;
  __syncthreads();

  { // frag order: ((t*4+ks)*64 + l)*16B <-> w[t*32+(l&31)][ks*16+(l>>5)*8+j]
    const int ks = tid >> 6, l = tid & 63;
    const float* r0 = s + (l & 31) * 64 + ks * 16 + ((l >> 5) << 3);
    v8h hv, lv;
#pragma unroll
    for (int j = 0; j < 8; ++j) {
      float v = r0[j];
      _Float16 h = (_Float16)v;
      hv[j] = h;
      lv[j] = (_Float16)(v - (float)h);
    }
    const size_t eoff = ((size_t)(t * 4 + ks) * 64 + l) * 16;
    *(v8h*)(ws + WS_WHI + eoff) = hv;
    *(v8h*)(ws + WS_WLO + eoff) = lv;
  }

  { // w^T
    const int d = tid >> 2, k0 = (tid & 3) * 8;
#pragma unroll
    for (int j = 0; j < 8; ++j)
      out[OFF_WT + d * 1024 + t * 32 + k0 + j] = s[(k0 + j) * 64 + d];
  }
}

// ---------------- fused scan: 512 blocks x 256 thr (4 waves x 32 rows = 128).
// LDS: [0,32768) slice hi, [32768,65536) slice lo, [65536,69632) hneg (all K),
//      [69632,70144) s_bi (128 int). Slice loop restages in place (L2-hot ws).
#define ROWS_PB 128

__global__ __launch_bounds__(256, 2) void vq_scan(const float* __restrict__ x,
                                                  const float* __restrict__ w,
                                                  const char* __restrict__ ws,
                                                  float* __restrict__ out) {
  __shared__ __align__(16) char lds[70144];
  const int tid = threadIdx.x;
  const int wv = tid >> 6, ln = tid & 63;
  const int col = ln & 31, hi = ln >> 5;
  const int rowBlk = blockIdx.x * ROWS_PB;
  const int rowsW = rowBlk + wv * 32;      // this wave's 32-row tile

  // ---- stage slice s (64 KB) : wave-uniform LDS base + lane*16 (m104-safe)
  auto stage = [&](int s) {
    const char* gH = ws + WS_WHI + s * 32768;
    const char* gL = ws + WS_WLO + s * 32768;
#pragma unroll
    for (int it = 0; it < 8; ++it) {
      const unsigned off = (unsigned)(it * 4096) + (unsigned)tid * 16;
      __builtin_amdgcn_global_load_lds((gbl_void_t*)(gH + off),
                                       (lds_void_t*)(lds + off), 16, 0, 0);
      __builtin_amdgcn_global_load_lds((gbl_void_t*)(gL + off),
                                       (lds_void_t*)(lds + 32768 + off), 16, 0, 0);
    }
  };

  stage(0);
  __builtin_amdgcn_global_load_lds((gbl_void_t*)(ws + WS_HNEG + tid * 16),
                                   (lds_void_t*)(lds + 65536 + tid * 16), 16, 0, 0);

  // ---- x B-frags (fp16 hi/lo) + ||x||^2 — overlaps the staging DMA
  v8h xh[4], xl[4];
  float xn = 0.f;
  {
    const float* xr = x + (size_t)(rowsW + col) * D + hi * 8;
#pragma unroll
    for (int ks = 0; ks < 4; ++ks) {
      float4 u0 = *(const float4*)(xr + ks * 16);
      float4 u1 = *(const float4*)(xr + ks * 16 + 4);
      float e[8] = {u0.x, u0.y, u0.z, u0.w, u1.x, u1.y, u1.z, u1.w};
#pragma unroll
      for (int j = 0; j < 8; ++j) {
        _Float16 h = (_Float16)e[j];
        xh[ks][j] = h;
        xl[ks][j] = (_Float16)(e[j] - (float)h);
        xn = fmaf(e[j], e[j], xn);
      }
    }
  }

  asm volatile("s_waitcnt vmcnt(0)" ::: "memory");
  __syncthreads();

  const float* hn = (const float*)(lds + 65536);

  // ones B-frag for the bias MFMA: B[k][*]=1 at k=0,1
  v8h ones = {};
  ones[0] = hi ? (_Float16)0.f : (_Float16)1.f;
  ones[1] = hi ? (_Float16)0.f : (_Float16)1.f;

  float best = -3.0e38f;
  int bi = 0;

#pragma unroll 1
  for (int s = 0; s < 4; ++s) {
#pragma unroll 2
    for (int ct = 0; ct < 8; ++ct) {
      v8h wh[4], wl[4];
#pragma unroll
      for (int ks = 0; ks < 4; ++ks) {
        wh[ks] = *(const v8h*)(lds + ct * 4096 + ks * 1024 + ln * 16);
        wl[ks] = *(const v8h*)(lds + 32768 + ct * 4096 + ks * 1024 + ln * 16);
      }
      const float hv = hn[s * 256 + ct * 32 + col];
      const _Float16 bh = (_Float16)hv;
      const _Float16 bl = (_Float16)(hv - (float)bh);
      v8h bias = {};
      bias[0] = hi ? (_Float16)0.f : bh;
      bias[1] = hi ? (_Float16)0.f : bl;

      v16f a0 = {};
      a0 = __builtin_amdgcn_mfma_f32_32x32x16_f16(bias, ones, a0, 0, 0, 0);
#pragma unroll
      for (int ks = 0; ks < 4; ++ks) {
        a0 = __builtin_amdgcn_mfma_f32_32x32x16_f16(wh[ks], xh[ks], a0, 0, 0, 0);
        a0 = __builtin_amdgcn_mfma_f32_32x32x16_f16(wl[ks], xh[ks], a0, 0, 0, 0);
        a0 = __builtin_amdgcn_mfma_f32_32x32x16_f16(wh[ks], xl[ks], a0, 0, 0, 0);
      }

      float m0 = fmaxf(fmaxf(fmaxf(a0[0], a0[1]), fmaxf(a0[2], a0[3])),
                       fmaxf(fmaxf(a0[4], a0[5]), fmaxf(a0[6], a0[7])));
      m0 = fmaxf(m0, fmaxf(fmaxf(fmaxf(a0[8], a0[9]), fmaxf(a0[10], a0[11])),
                           fmaxf(fmaxf(a0[12], a0[13]), fmaxf(a0[14], a0[15]))));
      const bool u0 = m0 > best;
      if (__any(u0)) {
        const int cbase = s * 256 + ct * 32 + 4 * hi;
#pragma unroll
        for (int r = 15; r >= 0; --r) {   // descending overwrite => first max wins
          const int code = cbase + (r & 3) + 8 * (r >> 2);
          bi = (u0 && a0[r] == m0) ? code : bi;
        }
        best = u0 ? m0 : best;
      }
    }

    if (s < 3) {   // restage in place: readers done -> DMA -> visible
      __syncthreads();
      stage(s + 1);
      asm volatile("s_waitcnt vmcnt(0)" ::: "memory");
      __syncthreads();
    }
  }

  // ---- merge the two hi-halves (each covered half the codes per ct)
  {
    float ob = __shfl_xor(best, 32, 64);
    int oi = __shfl_xor(bi, 32, 64);
    if (ob > best || (ob == best && oi < bi)) { best = ob; bi = oi; }
    xn += __shfl_xor(xn, 32, 64);
  }

  // ---- fused epilogue: idx, loss, cooperative quantized gather
  int* s_bi = (int*)(lds + 69632);
  if (hi == 0) {
    out[OFF_IDX + rowsW + col] = (float)bi;
    s_bi[wv * 32 + col] = bi;
  }
  float lr = (hi == 0) ? (xn - 2.f * best) : 0.f;  // ||x-w||^2 = ||x||^2 - 2*score
#pragma unroll
  for (int off = 32; off >= 1; off >>= 1) lr += __shfl_xor(lr, off, 64);
  if (ln == 0) atomicAdd(out + OFF_LOSS, lr * (BETA / (float)(N_VEC * D)));

  __syncthreads();
#pragma unroll 8
  for (int it = 0; it < 32; ++it) {      // 4 rows x 64 lanes = 1 KB per iter
    const int rl = it * 4 + wv;
    const float v = w[(size_t)s_bi[rl] * 64 + ln];
    out[OFF_Q + (size_t)(rowBlk + rl) * 64 + ln] = v;
  }
}

extern "C" void kernel_launch(void* const* d_in, const int* in_sizes, int n_in,
                              void* d_out, int out_size, void* d_ws, size_t ws_size,
                              hipStream_t stream) {
  const float* x = (const float*)d_in[0];
  const float* w = (const float*)d_in[1];
  float* out = (float*)d_out;
  char* ws = (char*)d_ws;

  vq_prep<<<32, 256, 0, stream>>>(w, ws, out);
  vq_scan<<<N_VEC / ROWS_PB, 256, 0, stream>>>(x, w, ws, out);
}